// Round 1
// baseline (1386.019 us; speedup 1.0000x reference)
//
#include <hip/hip_runtime.h>

// TopK mask: out = x where x is among row's top-k (ties -> lowest index), else 0.
// x: [8192, 24576] fp32, k = 64 (read from device), out fp32 same shape.
//
// v2: persistent-block cross-row pipeline.
//   - 256 blocks (1/CU), 32 rows each.
//   - Next row staged into LDS via global_load_lds (async DMA, no VGPR use),
//     issued before the select of the current row -> read(i+1) || select(i).
//   - Staging is wave-linear: lane l of wave w reads back exactly the bytes its
//     own wave's global_load_lds wrote -> stage path needs NO block barrier.
//   - All select barriers are raw s_barrier + lgkmcnt(0) (LDS visibility only);
//     __syncthreads would emit s_waitcnt vmcnt(0) and drain the prefetch.
//   - vmcnt(0) once per row at the consume point; prev row's stores drain there.
// Traffic = 1 read + 1 write = 1.61 GB -> ~256 us floor.

#define COLS  24576
#define TPB   1024
#define NCH   6            // float4 chunks per thread
#define EPT   24           // elements per thread
#define NSUB  32           // pass-0 sub-histograms (wave x lane parity)
#define HPAD  257          // +1 padding: spreads sub-hist banks
#define NBLK  256          // persistent blocks, 1 per CU

typedef float v4f __attribute__((ext_vector_type(4)));

// order-preserving float->uint (ascending): topk by value == topk by u
__device__ __forceinline__ unsigned int f2o(unsigned int b) {
    return (b & 0x80000000u) ? ~b : (b | 0x80000000u);
}
__device__ __forceinline__ float o2f(unsigned int u) {
    unsigned int b = (u & 0x80000000u) ? (u & 0x7fffffffu) : ~u;
    return __uint_as_float(b);
}

// raw barrier: LDS visibility only. Does NOT drain vmcnt -> the async row
// prefetch stays in flight across all select phases.
#define BAR() do { asm volatile("s_waitcnt lgkmcnt(0)" ::: "memory"); \
                   __builtin_amdgcn_s_barrier();                      \
                   asm volatile("" ::: "memory"); } while (0)

// async global->LDS stage of one row, 16B per lane per chunk.
// LDS dest is wave-uniform base + lane*16 (HW rule) == our linear layout.
#define PREFETCH_ROW(rowptr)                                                       \
    do {                                                                           \
        const unsigned int* _gp = (const unsigned int*)(rowptr);                   \
        _Pragma("unroll")                                                          \
        for (int _j = 0; _j < NCH; _j++) {                                         \
            const int _i4 = (_j * TPB + t) * 4;                                    \
            __builtin_amdgcn_global_load_lds(                                      \
                (const __attribute__((address_space(1))) unsigned int*)(_gp + _i4),\
                (__attribute__((address_space(3))) unsigned int*)(&stage[_i4]),    \
                16, 0, 0);                                                         \
        }                                                                          \
    } while (0)

extern "C" __global__ __launch_bounds__(TPB, 4)
void topk_mask(const float* __restrict__ x, const int* __restrict__ kptr,
               float* __restrict__ out, int nrows, int rpb)
{
    __shared__ __align__(16) unsigned int stage[COLS];   // 96 KiB row buffer
    __shared__ unsigned int whist[NSUB * HPAD];          // 32.1 KiB, pass-0 only
    __shared__ unsigned int hist[256];
    __shared__ unsigned int sb, sr, scnt;

    const int t    = threadIdx.x;
    const int lane = t & 63;
    const int wave = t >> 6;
    const unsigned int k = (unsigned int)kptr[0];
    const long long row0 = (long long)blockIdx.x * rpb;

    if (row0 < nrows) PREFETCH_ROW(x + row0 * COLS);

    // wave-0 suffix-scan over 256 bins (4 bins/lane, high->low); finds the bin
    // where the cumulative count from the top crosses rr.
    auto scan_select = [&](unsigned int rr) {
        unsigned int c0 = hist[4*lane+0], c1 = hist[4*lane+1];
        unsigned int c2 = hist[4*lane+2], c3 = hist[4*lane+3];
        unsigned int gs = c0 + c1 + c2 + c3;
        unsigned int s = gs;
        #pragma unroll
        for (int d = 1; d < 64; d <<= 1) {
            unsigned int o = __shfl_down(s, d);
            s += (lane + d < 64) ? o : 0u;
        }
        unsigned int T = s - gs;               // sum over lanes > lane
        if (T < rr && rr <= T + gs) {          // exactly one lane true
            unsigned int A = T, b, c;
            if (A + c3 >= rr)                { b = 3; c = c3; }
            else if (A + c3 + c2 >= rr)      { A += c3;           b = 2; c = c2; }
            else if (A + c3 + c2 + c1 >= rr) { A += c3 + c2;      b = 1; c = c1; }
            else                             { A += c3 + c2 + c1; b = 0; c = c0; }
            sb   = 4u * (unsigned)lane + b;    // selected bin
            sr   = rr - A;                     // rank remaining inside bin
            scnt = c;                          // candidates in bin
        }
    };

    for (int i = 0; i < rpb; i++) {
        const long long row = row0 + i;
        if (row >= nrows) break;

        // Wait for this row's staged data. Also drains prev row's stores --
        // that's HBM work we pay anyway, and vmcnt(0) keeps the accounting
        // robust against any compiler-generated scratch traffic.
        asm volatile("s_waitcnt vmcnt(0)" ::: "memory");
        __builtin_amdgcn_sched_barrier(0);

        // LDS -> VGPR, wave-private region: no block barrier needed.
        unsigned int uu[EPT];
        #pragma unroll
        for (int j = 0; j < NCH; j++) {
            const uint4 v = *(const uint4*)&stage[(j * TPB + t) * 4];
            uu[4*j+0] = f2o(v.x); uu[4*j+1] = f2o(v.y);
            uu[4*j+2] = f2o(v.z); uu[4*j+3] = f2o(v.w);
        }
        // ds_reads landed in VGPRs -> safe to overwrite stage with next row.
        asm volatile("s_waitcnt lgkmcnt(0)" ::: "memory");
        __builtin_amdgcn_sched_barrier(0);

        // Async prefetch of next row: overlaps the entire select + write below.
        if (i + 1 < rpb && row + 1 < nrows) PREFETCH_ROW(x + (row + 1) * COLS);

        // Zero this wave's two sub-hists (wave-private -> no barrier).
        {
            unsigned int* wz = &whist[(wave * 2) * HPAD];
            #pragma unroll
            for (int q = 0; q < (2 * HPAD + 63) / 64; q++) {
                int idx = q * 64 + lane;
                if (idx < 2 * HPAD) wz[idx] = 0u;
            }
        }

        // ---- radix pass 0: bits [31:24]; skewed bins -> 32 sub-hists ----
        unsigned int* myh = &whist[(((unsigned)wave << 1) | (unsigned)(lane & 1)) * HPAD];
        #pragma unroll
        for (int e = 0; e < EPT; e++) atomicAdd(&myh[uu[e] >> 24], 1u);
        BAR();

        if (t < 256) {  // combine 32 sub-hists
            unsigned int s = 0;
            #pragma unroll
            for (int h = 0; h < NSUB; h++) s += whist[h * HPAD + t];
            hist[t] = s;
        }
        BAR();

        unsigned int r = k;
        if (wave == 0) scan_select(r);
        BAR();
        unsigned int pref = sb;
        r = sr;

        // ---- radix passes 1..3: few candidates -> single shared hist ----
        #pragma unroll
        for (int shift = 16; shift >= 0; shift -= 8) {
            if (t < 256) hist[t] = 0u;
            BAR();
            #pragma unroll
            for (int e = 0; e < EPT; e++) {
                unsigned int u = uu[e];
                if ((u >> (shift + 8)) == pref)
                    atomicAdd(&hist[(u >> shift) & 255u], 1u);
            }
            BAR();
            if (wave == 0) scan_select(r);
            BAR();
            pref = (pref << 8) | sb;
            r = sr;
        }

        const unsigned int u_t  = pref;   // exact k-th largest (ordered encoding)
        const unsigned int need = r;      // #elements == u_t to include
        const unsigned int eq   = scnt;   // #elements == u_t total

        // Tie resolution (rare): smallest column cutoff m with
        // count(col < m && u == u_t) == need -> lowest indices win (matches XLA).
        unsigned int m = COLS;
        if (eq != need) {
            unsigned int lo = 0, hi = COLS;
            while (hi - lo > 1u) {
                unsigned int mid = (lo + hi) >> 1;
                BAR();
                if (t == 0) hist[0] = 0u;
                BAR();
                unsigned int loc = 0;
                #pragma unroll
                for (int j = 0; j < NCH; j++) {
                    #pragma unroll
                    for (int q = 0; q < 4; q++) {
                        unsigned int col = (unsigned)(j * (TPB * 4) + (t << 2) + q);
                        loc += (uu[4*j+q] == u_t && col < mid) ? 1u : 0u;
                    }
                }
                if (loc) atomicAdd(&hist[0], loc);
                BAR();
                if (hist[0] >= need) hi = mid; else lo = mid;
            }
            m = hi;
        }

        // ---- masked write, nontemporal dwordx4; no wait -> drains under the
        // next row's vmcnt stall ----
        v4f* op = (v4f*)(out + row * COLS);
        #pragma unroll
        for (int j = 0; j < NCH; j++) {
            unsigned int cbase = (unsigned)(j * (TPB * 4) + (t << 2));
            unsigned int u0 = uu[4*j+0], u1 = uu[4*j+1];
            unsigned int u2 = uu[4*j+2], u3 = uu[4*j+3];
            v4f w;
            w.x = (u0 > u_t || (u0 == u_t && cbase + 0u < m)) ? o2f(u0) : 0.0f;
            w.y = (u1 > u_t || (u1 == u_t && cbase + 1u < m)) ? o2f(u1) : 0.0f;
            w.z = (u2 > u_t || (u2 == u_t && cbase + 2u < m)) ? o2f(u2) : 0.0f;
            w.w = (u3 > u_t || (u3 == u_t && cbase + 3u < m)) ? o2f(u3) : 0.0f;
            __builtin_nontemporal_store(w, op + j * TPB + t);
        }
    }
}

extern "C" void kernel_launch(void* const* d_in, const int* in_sizes, int n_in,
                              void* d_out, int out_size, void* d_ws, size_t ws_size,
                              hipStream_t stream)
{
    const float* x    = (const float*)d_in[0];
    const int*   kptr = (const int*)d_in[1];
    float*       outp = (float*)d_out;
    const int rows = in_sizes[0] / COLS;          // 8192
    const int rpb  = (rows + NBLK - 1) / NBLK;    // 32
    topk_mask<<<NBLK, TPB, 0, stream>>>(x, kptr, outp, rows, rpb);
}